// Round 17
// baseline (122.138 us; speedup 1.0000x reference)
//
#include <hip/hip_runtime.h>

// MultiHeadAttentionClassical: B=2, S=2048, D=1024, H=16, Hd=64, fp32 in/out.
// cast->bf16 | fused QKV NT-GEMM (V written transposed) | flash attn | out proj.
// R17 = R16 + attn re-gridded: 64-q blocks x 2 waves (128 thr) -> grid 1024,
// 4 blocks/CU resident (R15 showed the 1024-block grid gave attn-core +12%;
// this captures it without SPLIT=2's partial-write + combine tax).
// Per-wave loop algebra byte-identical to the R4..R16-proven kernel.

typedef unsigned short u16;
typedef unsigned int   u32;
typedef __bf16 bf16;
typedef bf16 bf16x8 __attribute__((ext_vector_type(8)));
typedef float f32x4  __attribute__((ext_vector_type(4)));
typedef float f32x16 __attribute__((ext_vector_type(16)));
typedef u16  u16x8  __attribute__((ext_vector_type(8)));
typedef u16  u16x4  __attribute__((ext_vector_type(4)));
typedef u32  u32x4  __attribute__((ext_vector_type(4)));

#define DEV __device__ __forceinline__

#if __has_builtin(__builtin_amdgcn_exp2f)
#define EXP2(x) __builtin_amdgcn_exp2f(x)
#else
#define EXP2(x) exp2f(x)
#endif

DEV void gld_lds16(const void* g, void* l) {
  __builtin_amdgcn_global_load_lds(
      (__attribute__((address_space(1))) void*)(const_cast<void*>(g)),
      (__attribute__((address_space(3))) void*)(l), 16, 0, 0);
}

DEV u16 f2bf(float f) {  // RNE float->bf16
  u32 u = __builtin_bit_cast(u32, f);
  u32 lsb = (u >> 16) & 1u;
  u += 0x7fffu + lsb;
  return (u16)(u >> 16);
}

DEV u32 pbf2(float lo, float hi) {  // {bf16(lo)[15:0], bf16(hi)[31:16]}
  u32 d;
  asm("v_cvt_pk_bf16_f32 %0, %1, %2" : "=v"(d) : "v"(lo), "v"(hi));
  return d;
}

DEV void pl32swap(u32& a, u32& b) {  // a.hi-lanes <-> b.lo-lanes
  asm("v_permlane32_swap_b32 %0, %1" : "+v"(a), "+v"(b));
}

// ---------------------------------------------------------------- cast kernel
struct CastArgs {
  const float* src[5];
  u16* dst[5];
  int n4[5];
};

__global__ __launch_bounds__(256) void cast_f32_bf16_kernel(CastArgs a) {
  const int y = blockIdx.y;
  const float4* s = (const float4*)a.src[y];
  u16x4* d = (u16x4*)a.dst[y];
  const int n4 = a.n4[y];
  const int stride = gridDim.x * blockDim.x;
  for (int i = blockIdx.x * blockDim.x + threadIdx.x; i < n4; i += stride) {
    float4 f = s[i];
    u16x4 o;
    o[0] = f2bf(f.x); o[1] = f2bf(f.y); o[2] = f2bf(f.z); o[3] = f2bf(f.w);
    d[i] = o;
  }
}

// ------------------------------------------------------------- NT GEMM kernel
// (unchanged, proven R12/R16) C[m][n] = (sum_k A[m][k]*B[n][k] + bias[n]) * alpha
template<bool OUTF32, int BN>
__global__ __launch_bounds__(256, 3) void gemm_nt_kernel(
    const u16* __restrict__ A,
    const u16* __restrict__ B0, const u16* __restrict__ B1, const u16* __restrict__ B2,
    const float* __restrict__ bias0, const float* __restrict__ bias1, const float* __restrict__ bias2,
    void* __restrict__ C0, void* __restrict__ C1, void* __restrict__ C2,
    int M, int N, int K, float alpha0, float alpha1, float alpha2)
{
  constexpr int MT = (BN == 128) ? 4 : 2;  // 16-row M-frags per wave
  __shared__ __attribute__((aligned(16))) u16 As[2][4096];
  __shared__ __attribute__((aligned(16))) u16 Bs[2][BN * 32];

  const int z = blockIdx.z;
  const u16* Bmat   = (z == 0) ? B0 : (z == 1) ? B1 : B2;
  const float* bias = (z == 0) ? bias0 : (z == 1) ? bias1 : bias2;
  void* Cout        = (z == 0) ? C0 : (z == 1) ? C1 : C2;
  const float alpha = (z == 0) ? alpha0 : (z == 1) ? alpha1 : alpha2;

  const int tid  = threadIdx.x;
  const int lane = tid & 63;
  const int w    = tid >> 6;
  const int l15  = lane & 15, l4 = lane >> 4;
  const int m0   = blockIdx.y * 128;
  const int n0   = blockIdx.x * BN;

  const int rowbase = (BN == 128) ? (w >> 1) * 64 : w * 32;
  const int colbase = (BN == 128) ? (w & 1) * 64 : 0;

  // A staging: 512 units of 16B, 2 per thread
  const int u0 = tid;
  const int u1 = tid + 256;
  const int r0 = u0 >> 2, c0s = (u0 & 3) ^ (r0 & 3);
  const int r1 = u1 >> 2, c1s = (u1 & 3) ^ (r1 & 3);
  const size_t K2 = (size_t)K * 2;
  const char* pa0 = (const char*)A + (size_t)(m0 + r0) * K2 + c0s * 16;
  const char* pa1 = (const char*)A + (size_t)(m0 + r1) * K2 + c1s * 16;
  // B staging: BN*4 units (512 -> 2/thread, 256 -> 1/thread)
  const char* pb0 = (const char*)Bmat + (size_t)(n0 + r0) * K2 + c0s * 16;
  const char* pb1 = (const char*)Bmat + (size_t)(n0 + r1) * K2 + c1s * 16;

  f32x4 acc[MT][4] = {};

  const int aoff0 = (rowbase + l15) * 64 + ((l4 ^ (l15 & 3)) * 16);
  const int boff0 = (colbase + l15) * 64 + ((l4 ^ (l15 & 3)) * 16);

  gld_lds16(pa0, (char*)As[0] + u0 * 16);
  gld_lds16(pa1, (char*)As[0] + u1 * 16);
  gld_lds16(pb0, (char*)Bs[0] + u0 * 16);
  if (BN == 128) gld_lds16(pb1, (char*)Bs[0] + u1 * 16);
  __syncthreads();

  int buf = 0;
  for (int k0 = 0; k0 < K; k0 += 32) {
    if (k0 + 32 < K) {
      const size_t ko = (size_t)(k0 + 32) * 2;
      gld_lds16(pa0 + ko, (char*)As[buf ^ 1] + u0 * 16);
      gld_lds16(pa1 + ko, (char*)As[buf ^ 1] + u1 * 16);
      gld_lds16(pb0 + ko, (char*)Bs[buf ^ 1] + u0 * 16);
      if (BN == 128) gld_lds16(pb1 + ko, (char*)Bs[buf ^ 1] + u1 * 16);
    }
    bf16x8 af[MT], bfr[4];
#pragma unroll
    for (int mt = 0; mt < MT; ++mt)
      af[mt] = *(const bf16x8*)((const char*)As[buf] + aoff0 + mt * 16 * 64);
#pragma unroll
    for (int nt = 0; nt < 4; ++nt)
      bfr[nt] = *(const bf16x8*)((const char*)Bs[buf] + boff0 + nt * 16 * 64);
#pragma unroll
    for (int mt = 0; mt < MT; ++mt)
#pragma unroll
      for (int nt = 0; nt < 4; ++nt)
        acc[mt][nt] = __builtin_amdgcn_mfma_f32_16x16x32_bf16(af[mt], bfr[nt], acc[mt][nt], 0, 0, 0);
    __syncthreads();
    buf ^= 1;
  }

  if (!OUTF32 && z == 2) {
#pragma unroll
    for (int nt = 0; nt < 4; ++nt) {
      const int col = n0 + colbase + nt * 16 + l15;
      const float bv = bias[col];
#pragma unroll
      for (int mt = 0; mt < MT; ++mt) {
        const int row0 = m0 + rowbase + mt * 16 + l4 * 4;
        const int b = row0 >> 11, s0 = row0 & 2047;
        u16x4 o;
#pragma unroll
        for (int r = 0; r < 4; ++r) o[r] = f2bf(acc[mt][nt][r] + bv);
        *(u16x4*)((u16*)Cout + (size_t)b * 2097152 + (size_t)col * 2048 + s0) = o;
      }
    }
  } else {
#pragma unroll
    for (int nt = 0; nt < 4; ++nt) {
      const int col = n0 + colbase + nt * 16 + l15;
      const float bv = bias[col];
#pragma unroll
      for (int mt = 0; mt < MT; ++mt) {
        const int row = m0 + rowbase + mt * 16 + l4 * 4;
#pragma unroll
        for (int r = 0; r < 4; ++r) {
          float v = (acc[mt][nt][r] + bv) * alpha;
          if (OUTF32) ((float*)Cout)[(size_t)(row + r) * N + col] = v;
          else        ((u16*)Cout)[(size_t)(row + r) * N + col] = f2bf(v);
        }
      }
    }
  }
}

// ---------------------------------------------------------- flash attention
// Block: 64 q-rows of one (b,h); 2 waves x 32 q (128 threads). Grid 32x32 =
// 1024 blocks -> 4 blocks/CU (LDS 34.8KB x 4 = 139KB). Per-wave loop identical
// to the proven kernel: KV tiles of 64, two 32-kv subtiles, swapped QK^T,
// static-shift softmax, in-reg P via cvt_pk+permlane32_swap, l via ones-A MFMA.
// Staging: 8 gld_lds16/thread (4 K-units + 4 V-units, u = tid + k*128).
__global__ __launch_bounds__(128, 2) void attn_fwd_kernel(
    const u16* __restrict__ Qg, const u16* __restrict__ Kg, const u16* __restrict__ Vtg,
    const int* __restrict__ maskg, u16* __restrict__ Og)
{
  __shared__ __attribute__((aligned(16))) u16 lds[17408];  // K[2]|V[2] 32KB; epi scratch
  __shared__ u32 tzb[2];

  const int tid  = threadIdx.x;
  const int lane = tid & 63;
  const int w    = tid >> 6;          // 2 waves
  const int l31  = lane & 31, half = lane >> 5;
  const int qt   = blockIdx.x;
  const int bh   = blockIdx.y;
  const int b    = bh >> 4, h = bh & 15;
  const int qbase = qt * 64 + w * 32;

  // ---- mask bitmap prologue: 128 thr x 16 ints = 2048. Wave w covers kv
  // tiles [w*16, w*16+16); tile t_local = 4 lanes (lane t*4..t*4+3).
  {
    const int4* mp = (const int4*)(maskg + b * 2048 + tid * 16);
    bool az = false;
#pragma unroll
    for (int q4 = 0; q4 < 4; ++q4) {
      const int4 a = mp[q4];
      az |= (a.x == 0) | (a.y == 0) | (a.z == 0) | (a.w == 0);
    }
    const unsigned long long bal = __ballot(az);
    if (lane == 0) {
      u32 bits = 0;
#pragma unroll
      for (int t = 0; t < 16; ++t)
        if ((bal >> (4 * t)) & 0xFull) bits |= (1u << t);
      tzb[w] = bits;
    }
  }

  // staging (16B units): K tile 512 units @ base 0, V^T tile 512 units @ 16KB.
  // 4 K-units + 4 V-units per thread: u = tid + k*128.
  const char* kpp[4];
  const char* vpp[4];
  int uoff[4];
#pragma unroll
  for (int k = 0; k < 4; ++k) {
    const int u = tid + k * 128;
    const int r = u >> 3, c = (u & 7) ^ (r & 7);
    uoff[k] = u * 16;
    kpp[k] = (const char*)Kg + ((size_t)(b * 2048 + r) * 1024 + h * 64 + c * 8) * 2;
    vpp[k] = (const char*)Vtg + ((size_t)b * 2097152 + (size_t)h * 131072 + (size_t)r * 2048 + c * 8) * 2;
  }

  // Q fragments (B-operand: lane holds col q=l31, hd = c*16 + half*8 + j)
  bf16x8 qf[4];
  {
    const char* qrow = (const char*)Qg + ((size_t)(b * 2048 + qbase + l31) * 1024 + h * 64) * 2;
#pragma unroll
    for (int c = 0; c < 4; ++c)
      qf[c] = *(const bf16x8*)(qrow + c * 32 + half * 16);
  }

  bf16x8 ones;
#pragma unroll
  for (int i = 0; i < 8; ++i) ones[i] = (bf16)1.0f;

  const int* mrow_ptr = maskg + b * 2048;

  // prologue: stage tile 0
#pragma unroll
  for (int k = 0; k < 4; ++k) {
    gld_lds16(kpp[k], (char*)lds + uoff[k]);
    gld_lds16(vpp[k], (char*)lds + 16384 + uoff[k]);
  }
  __syncthreads();

  const u32 tilezero = tzb[0] | (tzb[1] << 16);

  f32x16 oT[2] = {};
  f32x16 lacc = {};

  int buf = 0;
  for (int kt = 0; kt < 32; ++kt) {
    if (kt < 31) {
      const size_t ko = (size_t)(kt + 1) * 131072;  // K: 64 rows * 2048 B
      const size_t vo = (size_t)(kt + 1) * 128;     // V^T: 64 cols * 2 B
#pragma unroll
      for (int k = 0; k < 4; ++k) {
        gld_lds16(kpp[k] + ko, (char*)lds + (buf ^ 1) * 8192 + uoff[k]);
        gld_lds16(vpp[k] + vo, (char*)lds + 16384 + (buf ^ 1) * 8192 + uoff[k]);
      }
    }

    const char* ktile = (const char*)lds + buf * 8192;
    const char* vtile = (const char*)lds + 16384 + buf * 8192;

#pragma unroll
    for (int sub = 0; sub < 2; ++sub) {
      // S^T = K Q^T : A = K rows kv=sub*32+l31, k-chunk = c*2+half
      f32x16 st = {};
      const int krow = sub * 32 + l31;
      const char* kbase = ktile + krow * 128;
#pragma unroll
      for (int c = 0; c < 4; ++c) {
        bf16x8 kf = *(const bf16x8*)(kbase + (((c * 2 + half) ^ (krow & 7)) * 16));
        st = __builtin_amdgcn_mfma_f32_32x32x16_bf16(kf, qf[c], st, 0, 0, 0);
      }

      // mask (cold): S^T reg r -> kv = base + (r&3)+8*(r>>2)+4*half
      if (tilezero & (1u << kt)) {
        const int kvb = kt * 64 + sub * 32 + half * 4;
#pragma unroll
        for (int r = 0; r < 16; ++r)
          if (mrow_ptr[kvb + (r & 3) + 8 * (r >> 2)] == 0) st[r] = -1e9f;
      }

      // static-shift softmax
#pragma unroll
      for (int r = 0; r < 16; ++r)
        st[r] = EXP2(st[r] - 8.0f);

      // P^T B-frags via pack + permlane32_swap
      u32 a0 = pbf2(st[0], st[1]),   b0 = pbf2(st[4], st[5]);
      u32 a1 = pbf2(st[2], st[3]),   b1 = pbf2(st[6], st[7]);
      u32 a2 = pbf2(st[8], st[9]),   b2 = pbf2(st[12], st[13]);
      u32 a3 = pbf2(st[10], st[11]), b3 = pbf2(st[14], st[15]);
      pl32swap(a0, b0); pl32swap(a1, b1); pl32swap(a2, b2); pl32swap(a3, b3);
      u32x4 wlo = {a0, a1, b0, b1}, whi = {a2, a3, b2, b3};
      bf16x8 Blo = __builtin_bit_cast(bf16x8, wlo);
      bf16x8 Bhi = __builtin_bit_cast(bf16x8, whi);

      // l += 1^T P^T : every output element = column sum of P^T = l[q]
      lacc = __builtin_amdgcn_mfma_f32_32x32x16_bf16(ones, Blo, lacc, 0, 0, 0);
      lacc = __builtin_amdgcn_mfma_f32_32x32x16_bf16(ones, Bhi, lacc, 0, 0, 0);

      // O^T += V^T P^T : A = V^T rows hd=hdt*32+l31, kv chunks sub*4+{0,2}+half
#pragma unroll
      for (int hdt = 0; hdt < 2; ++hdt) {
        const int vrow = hdt * 32 + l31;
        const char* vbase = vtile + vrow * 128;
        bf16x8 vlo = *(const bf16x8*)(vbase + (((sub * 4 + half) ^ (vrow & 7)) * 16));
        bf16x8 vhi = *(const bf16x8*)(vbase + (((sub * 4 + 2 + half) ^ (vrow & 7)) * 16));
        oT[hdt] = __builtin_amdgcn_mfma_f32_32x32x16_bf16(vlo, Blo, oT[hdt], 0, 0, 0);
        oT[hdt] = __builtin_amdgcn_mfma_f32_32x32x16_bf16(vhi, Bhi, oT[hdt], 0, 0, 0);
      }
    }

    __syncthreads();
    buf ^= 1;
  }

  // epilogue: normalize, LDS transpose (u16, wave-local scratch), coalesced store
  const float inv = 1.0f / lacc[0];  // all lacc elements = Σ_kv P[kv][q=l31]
  u16* sc = lds + w * 2304;  // 32 rows x stride 72 per wave
#pragma unroll
  for (int hdt = 0; hdt < 2; ++hdt)
#pragma unroll
    for (int run = 0; run < 4; ++run) {
      u16x4 o4;
#pragma unroll
      for (int i = 0; i < 4; ++i) o4[i] = f2bf(oT[hdt][run * 4 + i] * inv);
      const int hd0 = hdt * 32 + run * 8 + half * 4;
      *(u16x4*)(sc + l31 * 72 + hd0) = o4;
    }
  __syncthreads();
#pragma unroll
  for (int rep = 0; rep < 4; ++rep) {
    const int q = rep * 8 + (lane >> 3);
    u16x8 v = *(const u16x8*)(sc + q * 72 + (lane & 7) * 8);
    const size_t tok = (size_t)(b * 2048 + qbase + q);
    *(u16x8*)(Og + tok * 1024 + h * 64 + (lane & 7) * 8) = v;
  }
}

// ------------------------------------------------------------------- launch
extern "C" void kernel_launch(void* const* d_in, const int* in_sizes, int n_in,
                              void* d_out, int out_size, void* d_ws, size_t ws_size,
                              hipStream_t stream) {
  const float* x  = (const float*)d_in[0];
  const int* mask = (const int*)d_in[1];
  const float* Wq = (const float*)d_in[2];
  const float* bq = (const float*)d_in[3];
  const float* Wk = (const float*)d_in[4];
  const float* bk = (const float*)d_in[5];
  const float* Wv = (const float*)d_in[6];
  const float* bv = (const float*)d_in[7];
  const float* Wo = (const float*)d_in[8];
  const float* bo = (const float*)d_in[9];
  float* out = (float*)d_out;

  const int Mtok = 2 * 2048;  // 4096 tokens
  const int D = 1024;

  const size_t need = (size_t)Mtok * D * 2 * 5 + (size_t)D * D * 2 * 4;  // 48 MiB
  if (ws_size < need) return;

  char* p = (char*)d_ws;
  u16* xb  = (u16*)p; p += (size_t)Mtok * D * 2;
  u16* wqb = (u16*)p; p += (size_t)D * D * 2;
  u16* wkb = (u16*)p; p += (size_t)D * D * 2;
  u16* wvb = (u16*)p; p += (size_t)D * D * 2;
  u16* wob = (u16*)p; p += (size_t)D * D * 2;
  u16* Qb  = (u16*)p; p += (size_t)Mtok * D * 2;
  u16* Kb  = (u16*)p; p += (size_t)Mtok * D * 2;
  u16* Vtb = (u16*)p; p += (size_t)Mtok * D * 2;  // [b][h*64+hd][s]
  u16* Ob  = (u16*)p; p += (size_t)Mtok * D * 2;

  CastArgs ca;
  ca.src[0] = x;  ca.dst[0] = xb;  ca.n4[0] = Mtok * D / 4;
  ca.src[1] = Wq; ca.dst[1] = wqb; ca.n4[1] = D * D / 4;
  ca.src[2] = Wk; ca.dst[2] = wkb; ca.n4[2] = D * D / 4;
  ca.src[3] = Wv; ca.dst[3] = wvb; ca.n4[3] = D * D / 4;
  ca.src[4] = Wo; ca.dst[4] = wob; ca.n4[4] = D * D / 4;
  cast_f32_bf16_kernel<<<dim3(256, 5), 256, 0, stream>>>(ca);

  // fused QKV (BN=128, grid 768 = 3/CU): z=0 -> Q (alpha folds 1/8*log2e),
  // z=1 -> K, z=2 -> V^T
  const float qalpha = 0.125f * 1.44269504088896340736f;
  gemm_nt_kernel<false, 128><<<dim3(D / 128, Mtok / 128, 3), 256, 0, stream>>>(
      xb, wqb, wkb, wvb, bq, bk, bv, Qb, Kb, Vtb, Mtok, D, D, qalpha, 1.0f, 1.0f);

  // attn: 64-q blocks, 2 waves, grid 32x32 = 1024 -> 4 blocks/CU
  attn_fwd_kernel<<<dim3(2048 / 64, 32), 128, 0, stream>>>(Qb, Kb, Vtb, mask, Ob);

  // out projection (BN=64, grid 512 = 2/CU)
  gemm_nt_kernel<true, 64><<<dim3(D / 64, Mtok / 128, 1), 256, 0, stream>>>(
      Ob, wob, wob, wob, bo, bo, bo, out, out, out, Mtok, D, D, 1.0f, 1.0f, 1.0f);
}

// Round 18
// 117.517 us; speedup vs baseline: 1.0393x; 1.0393x over previous
//
#include <hip/hip_runtime.h>

// MultiHeadAttentionClassical: B=2, S=2048, D=1024, H=16, Hd=64, fp32 in/out.
// cast->bf16 | fused QKV NT-GEMM (V written transposed) | flash attn | out proj.
// FINAL (= R12/R16, best measured 117.75 us): attn SPLIT=1 (no combine); GEMM
// templated on BN -- out-proj uses 128x64 tiles (grid 512 = 2 blocks/CU).

typedef unsigned short u16;
typedef unsigned int   u32;
typedef __bf16 bf16;
typedef bf16 bf16x8 __attribute__((ext_vector_type(8)));
typedef float f32x4  __attribute__((ext_vector_type(4)));
typedef float f32x16 __attribute__((ext_vector_type(16)));
typedef u16  u16x8  __attribute__((ext_vector_type(8)));
typedef u16  u16x4  __attribute__((ext_vector_type(4)));
typedef u32  u32x4  __attribute__((ext_vector_type(4)));

#define DEV __device__ __forceinline__

#if __has_builtin(__builtin_amdgcn_exp2f)
#define EXP2(x) __builtin_amdgcn_exp2f(x)
#else
#define EXP2(x) exp2f(x)
#endif

DEV void gld_lds16(const void* g, void* l) {
  __builtin_amdgcn_global_load_lds(
      (__attribute__((address_space(1))) void*)(const_cast<void*>(g)),
      (__attribute__((address_space(3))) void*)(l), 16, 0, 0);
}

DEV u16 f2bf(float f) {  // RNE float->bf16
  u32 u = __builtin_bit_cast(u32, f);
  u32 lsb = (u >> 16) & 1u;
  u += 0x7fffu + lsb;
  return (u16)(u >> 16);
}

DEV u32 pbf2(float lo, float hi) {  // {bf16(lo)[15:0], bf16(hi)[31:16]}
  u32 d;
  asm("v_cvt_pk_bf16_f32 %0, %1, %2" : "=v"(d) : "v"(lo), "v"(hi));
  return d;
}

DEV void pl32swap(u32& a, u32& b) {  // a.hi-lanes <-> b.lo-lanes
  asm("v_permlane32_swap_b32 %0, %1" : "+v"(a), "+v"(b));
}

// ---------------------------------------------------------------- cast kernel
struct CastArgs {
  const float* src[5];
  u16* dst[5];
  int n4[5];
};

__global__ __launch_bounds__(256) void cast_f32_bf16_kernel(CastArgs a) {
  const int y = blockIdx.y;
  const float4* s = (const float4*)a.src[y];
  u16x4* d = (u16x4*)a.dst[y];
  const int n4 = a.n4[y];
  const int stride = gridDim.x * blockDim.x;
  for (int i = blockIdx.x * blockDim.x + threadIdx.x; i < n4; i += stride) {
    float4 f = s[i];
    u16x4 o;
    o[0] = f2bf(f.x); o[1] = f2bf(f.y); o[2] = f2bf(f.z); o[3] = f2bf(f.w);
    d[i] = o;
  }
}

// ------------------------------------------------------------- NT GEMM kernel
// C[m][n] = (sum_k A[m][k]*B[n][k] + bias[n]) * alpha.  BM=128, BK=32,
// BN in {128, 64}.  BN=128: 4 waves as 2x2, 64x64 each (proven R1-R9).
// BN=64: 4 waves as 4x1, 32x64 each; B staged with one gld/thread.
// z==2 (bf16, BN=128 path) writes output transposed per batch: Vt[b][n][s].
template<bool OUTF32, int BN>
__global__ __launch_bounds__(256, 3) void gemm_nt_kernel(
    const u16* __restrict__ A,
    const u16* __restrict__ B0, const u16* __restrict__ B1, const u16* __restrict__ B2,
    const float* __restrict__ bias0, const float* __restrict__ bias1, const float* __restrict__ bias2,
    void* __restrict__ C0, void* __restrict__ C1, void* __restrict__ C2,
    int M, int N, int K, float alpha0, float alpha1, float alpha2)
{
  constexpr int MT = (BN == 128) ? 4 : 2;  // 16-row M-frags per wave
  __shared__ __attribute__((aligned(16))) u16 As[2][4096];
  __shared__ __attribute__((aligned(16))) u16 Bs[2][BN * 32];

  const int z = blockIdx.z;
  const u16* Bmat   = (z == 0) ? B0 : (z == 1) ? B1 : B2;
  const float* bias = (z == 0) ? bias0 : (z == 1) ? bias1 : bias2;
  void* Cout        = (z == 0) ? C0 : (z == 1) ? C1 : C2;
  const float alpha = (z == 0) ? alpha0 : (z == 1) ? alpha1 : alpha2;

  const int tid  = threadIdx.x;
  const int lane = tid & 63;
  const int w    = tid >> 6;
  const int l15  = lane & 15, l4 = lane >> 4;
  const int m0   = blockIdx.y * 128;
  const int n0   = blockIdx.x * BN;

  const int rowbase = (BN == 128) ? (w >> 1) * 64 : w * 32;
  const int colbase = (BN == 128) ? (w & 1) * 64 : 0;

  // A staging: 512 units of 16B, 2 per thread
  const int u0 = tid;
  const int u1 = tid + 256;
  const int r0 = u0 >> 2, c0s = (u0 & 3) ^ (r0 & 3);
  const int r1 = u1 >> 2, c1s = (u1 & 3) ^ (r1 & 3);
  const size_t K2 = (size_t)K * 2;
  const char* pa0 = (const char*)A + (size_t)(m0 + r0) * K2 + c0s * 16;
  const char* pa1 = (const char*)A + (size_t)(m0 + r1) * K2 + c1s * 16;
  // B staging: BN*4 units (512 -> 2/thread, 256 -> 1/thread)
  const char* pb0 = (const char*)Bmat + (size_t)(n0 + r0) * K2 + c0s * 16;
  const char* pb1 = (const char*)Bmat + (size_t)(n0 + r1) * K2 + c1s * 16;

  f32x4 acc[MT][4] = {};

  const int aoff0 = (rowbase + l15) * 64 + ((l4 ^ (l15 & 3)) * 16);
  const int boff0 = (colbase + l15) * 64 + ((l4 ^ (l15 & 3)) * 16);

  gld_lds16(pa0, (char*)As[0] + u0 * 16);
  gld_lds16(pa1, (char*)As[0] + u1 * 16);
  gld_lds16(pb0, (char*)Bs[0] + u0 * 16);
  if (BN == 128) gld_lds16(pb1, (char*)Bs[0] + u1 * 16);
  __syncthreads();

  int buf = 0;
  for (int k0 = 0; k0 < K; k0 += 32) {
    if (k0 + 32 < K) {
      const size_t ko = (size_t)(k0 + 32) * 2;
      gld_lds16(pa0 + ko, (char*)As[buf ^ 1] + u0 * 16);
      gld_lds16(pa1 + ko, (char*)As[buf ^ 1] + u1 * 16);
      gld_lds16(pb0 + ko, (char*)Bs[buf ^ 1] + u0 * 16);
      if (BN == 128) gld_lds16(pb1 + ko, (char*)Bs[buf ^ 1] + u1 * 16);
    }
    bf16x8 af[MT], bfr[4];
#pragma unroll
    for (int mt = 0; mt < MT; ++mt)
      af[mt] = *(const bf16x8*)((const char*)As[buf] + aoff0 + mt * 16 * 64);
#pragma unroll
    for (int nt = 0; nt < 4; ++nt)
      bfr[nt] = *(const bf16x8*)((const char*)Bs[buf] + boff0 + nt * 16 * 64);
#pragma unroll
    for (int mt = 0; mt < MT; ++mt)
#pragma unroll
      for (int nt = 0; nt < 4; ++nt)
        acc[mt][nt] = __builtin_amdgcn_mfma_f32_16x16x32_bf16(af[mt], bfr[nt], acc[mt][nt], 0, 0, 0);
    __syncthreads();
    buf ^= 1;
  }

  if (!OUTF32 && z == 2) {
#pragma unroll
    for (int nt = 0; nt < 4; ++nt) {
      const int col = n0 + colbase + nt * 16 + l15;
      const float bv = bias[col];
#pragma unroll
      for (int mt = 0; mt < MT; ++mt) {
        const int row0 = m0 + rowbase + mt * 16 + l4 * 4;
        const int b = row0 >> 11, s0 = row0 & 2047;
        u16x4 o;
#pragma unroll
        for (int r = 0; r < 4; ++r) o[r] = f2bf(acc[mt][nt][r] + bv);
        *(u16x4*)((u16*)Cout + (size_t)b * 2097152 + (size_t)col * 2048 + s0) = o;
      }
    }
  } else {
#pragma unroll
    for (int nt = 0; nt < 4; ++nt) {
      const int col = n0 + colbase + nt * 16 + l15;
      const float bv = bias[col];
#pragma unroll
      for (int mt = 0; mt < MT; ++mt) {
        const int row = m0 + rowbase + mt * 16 + l4 * 4;
#pragma unroll
        for (int r = 0; r < 4; ++r) {
          float v = (acc[mt][nt][r] + bv) * alpha;
          if (OUTF32) ((float*)Cout)[(size_t)(row + r) * N + col] = v;
          else        ((u16*)Cout)[(size_t)(row + r) * N + col] = f2bf(v);
        }
      }
    }
  }
}

// ---------------------------------------------------------- flash attention
// Block: 128 q-rows of one (b,h). 4 waves x 32 q. KV tiles of 64, two 32-kv
// subtiles. Swapped QK^T (S^T in regs); P in-reg via cvt_pk+permlane32_swap;
// l via ones-A MFMA. Normalizes and writes bf16 Ob directly (no split).
__global__ __launch_bounds__(256, 2) void attn_fwd_kernel(
    const u16* __restrict__ Qg, const u16* __restrict__ Kg, const u16* __restrict__ Vtg,
    const int* __restrict__ maskg, u16* __restrict__ Og)
{
  __shared__ __attribute__((aligned(16))) u16 lds[17408];  // K[2]|V[2] 16KB; epi scratch
  __shared__ u32 tzb[4];

  const int tid  = threadIdx.x;
  const int lane = tid & 63;
  const int w    = tid >> 6;
  const int l31  = lane & 31, half = lane >> 5;
  const int qt   = blockIdx.x;
  const int bh   = blockIdx.y;
  const int b    = bh >> 4, h = bh & 15;
  const int qbase = qt * 128 + w * 32;

  // ---- mask bitmap prologue: bit kt set iff kv-tile kt contains a zero
  {
    const int4* mp = (const int4*)(maskg + b * 2048 + tid * 8);
    const int4 a = mp[0], c = mp[1];
    const bool az = (a.x == 0) | (a.y == 0) | (a.z == 0) | (a.w == 0) |
                    (c.x == 0) | (c.y == 0) | (c.z == 0) | (c.w == 0);
    const unsigned long long bal = __ballot(az);
    if (lane == 0) {
      u32 bits = 0;
#pragma unroll
      for (int t = 0; t < 8; ++t)
        if ((bal >> (8 * t)) & 0xFFull) bits |= (1u << t);
      tzb[w] = bits;
    }
  }

  // staging (16B units): K tile 512 units, V^T tile 512 units; 2+2 per thread
  const int u0 = tid, u1 = tid + 256;
  const int r0 = u0 >> 3, c0 = (u0 & 7) ^ (r0 & 7);
  const int r1 = u1 >> 3, c1 = (u1 & 7) ^ (r1 & 7);
  const char* kp0 = (const char*)Kg + ((size_t)(b * 2048 + r0) * 1024 + h * 64 + c0 * 8) * 2;
  const char* kp1 = (const char*)Kg + ((size_t)(b * 2048 + r1) * 1024 + h * 64 + c1 * 8) * 2;
  const char* vp0 = (const char*)Vtg + ((size_t)b * 2097152 + (size_t)h * 131072 + (size_t)r0 * 2048 + c0 * 8) * 2;
  const char* vp1 = (const char*)Vtg + ((size_t)b * 2097152 + (size_t)h * 131072 + (size_t)r1 * 2048 + c1 * 8) * 2;

  // Q fragments (B-operand: lane holds col q=l31, hd = c*16 + half*8 + j)
  bf16x8 qf[4];
  {
    const char* qrow = (const char*)Qg + ((size_t)(b * 2048 + qbase + l31) * 1024 + h * 64) * 2;
#pragma unroll
    for (int c = 0; c < 4; ++c)
      qf[c] = *(const bf16x8*)(qrow + c * 32 + half * 16);
  }

  bf16x8 ones;
#pragma unroll
  for (int i = 0; i < 8; ++i) ones[i] = (bf16)1.0f;

  const int* mrow_ptr = maskg + b * 2048;

  // prologue: stage tile 0
  gld_lds16(kp0, (char*)lds + u0 * 16);
  gld_lds16(kp1, (char*)lds + u1 * 16);
  gld_lds16(vp0, (char*)(lds + 8192) + u0 * 16);
  gld_lds16(vp1, (char*)(lds + 8192) + u1 * 16);
  __syncthreads();

  const u32 tilezero = tzb[0] | (tzb[1] << 8) | (tzb[2] << 16) | (tzb[3] << 24);

  f32x16 oT[2] = {};
  f32x16 lacc = {};

  int buf = 0;
  for (int kt = 0; kt < 32; ++kt) {
    if (kt < 31) {
      const size_t ko = (size_t)(kt + 1) * 131072;  // K: 64 rows * 2048 B
      const size_t vo = (size_t)(kt + 1) * 128;     // V^T: 64 cols * 2 B
      gld_lds16(kp0 + ko, (char*)(lds + (buf ^ 1) * 4096) + u0 * 16);
      gld_lds16(kp1 + ko, (char*)(lds + (buf ^ 1) * 4096) + u1 * 16);
      gld_lds16(vp0 + vo, (char*)(lds + 8192 + (buf ^ 1) * 4096) + u0 * 16);
      gld_lds16(vp1 + vo, (char*)(lds + 8192 + (buf ^ 1) * 4096) + u1 * 16);
    }

    const char* ktile = (const char*)(lds + buf * 4096);
    const char* vtile = (const char*)(lds + 8192 + buf * 4096);

#pragma unroll
    for (int sub = 0; sub < 2; ++sub) {
      // S^T = K Q^T : A = K rows kv=sub*32+l31, k-chunk = c*2+half
      f32x16 st = {};
      const int krow = sub * 32 + l31;
      const char* kbase = ktile + krow * 128;
#pragma unroll
      for (int c = 0; c < 4; ++c) {
        bf16x8 kf = *(const bf16x8*)(kbase + (((c * 2 + half) ^ (krow & 7)) * 16));
        st = __builtin_amdgcn_mfma_f32_32x32x16_bf16(kf, qf[c], st, 0, 0, 0);
      }

      // mask (cold): S^T reg r -> kv = base + (r&3)+8*(r>>2)+4*half
      if (tilezero & (1u << kt)) {
        const int kvb = kt * 64 + sub * 32 + half * 4;
#pragma unroll
        for (int r = 0; r < 16; ++r)
          if (mrow_ptr[kvb + (r & 3) + 8 * (r >> 2)] == 0) st[r] = -1e9f;
      }

      // static-shift softmax
#pragma unroll
      for (int r = 0; r < 16; ++r)
        st[r] = EXP2(st[r] - 8.0f);

      // P^T B-frags via pack + permlane32_swap
      u32 a0 = pbf2(st[0], st[1]),   b0 = pbf2(st[4], st[5]);
      u32 a1 = pbf2(st[2], st[3]),   b1 = pbf2(st[6], st[7]);
      u32 a2 = pbf2(st[8], st[9]),   b2 = pbf2(st[12], st[13]);
      u32 a3 = pbf2(st[10], st[11]), b3 = pbf2(st[14], st[15]);
      pl32swap(a0, b0); pl32swap(a1, b1); pl32swap(a2, b2); pl32swap(a3, b3);
      u32x4 wlo = {a0, a1, b0, b1}, whi = {a2, a3, b2, b3};
      bf16x8 Blo = __builtin_bit_cast(bf16x8, wlo);
      bf16x8 Bhi = __builtin_bit_cast(bf16x8, whi);

      // l += 1^T P^T : every output element = column sum of P^T = l[q]
      lacc = __builtin_amdgcn_mfma_f32_32x32x16_bf16(ones, Blo, lacc, 0, 0, 0);
      lacc = __builtin_amdgcn_mfma_f32_32x32x16_bf16(ones, Bhi, lacc, 0, 0, 0);

      // O^T += V^T P^T : A = V^T rows hd=hdt*32+l31, kv chunks sub*4+{0,2}+half
#pragma unroll
      for (int hdt = 0; hdt < 2; ++hdt) {
        const int vrow = hdt * 32 + l31;
        const char* vbase = vtile + vrow * 128;
        bf16x8 vlo = *(const bf16x8*)(vbase + (((sub * 4 + half) ^ (vrow & 7)) * 16));
        bf16x8 vhi = *(const bf16x8*)(vbase + (((sub * 4 + 2 + half) ^ (vrow & 7)) * 16));
        oT[hdt] = __builtin_amdgcn_mfma_f32_32x32x16_bf16(vlo, Blo, oT[hdt], 0, 0, 0);
        oT[hdt] = __builtin_amdgcn_mfma_f32_32x32x16_bf16(vhi, Bhi, oT[hdt], 0, 0, 0);
      }
    }

    __syncthreads();
    buf ^= 1;
  }

  // epilogue: normalize, LDS transpose (u16), coalesced bf16 store
  const float inv = 1.0f / lacc[0];  // all lacc elements = Σ_kv P[kv][q=l31]
  u16* sc = lds + w * 2304;  // 32 rows x stride 72
#pragma unroll
  for (int hdt = 0; hdt < 2; ++hdt)
#pragma unroll
    for (int run = 0; run < 4; ++run) {
      u16x4 o4;
#pragma unroll
      for (int i = 0; i < 4; ++i) o4[i] = f2bf(oT[hdt][run * 4 + i] * inv);
      const int hd0 = hdt * 32 + run * 8 + half * 4;
      *(u16x4*)(sc + l31 * 72 + hd0) = o4;
    }
  __syncthreads();
#pragma unroll
  for (int rep = 0; rep < 4; ++rep) {
    const int q = rep * 8 + (lane >> 3);
    u16x8 v = *(const u16x8*)(sc + q * 72 + (lane & 7) * 8);
    const size_t tok = (size_t)(b * 2048 + qbase + q);
    *(u16x8*)(Og + tok * 1024 + h * 64 + (lane & 7) * 8) = v;
  }
}

// ------------------------------------------------------------------- launch
extern "C" void kernel_launch(void* const* d_in, const int* in_sizes, int n_in,
                              void* d_out, int out_size, void* d_ws, size_t ws_size,
                              hipStream_t stream) {
  const float* x  = (const float*)d_in[0];
  const int* mask = (const int*)d_in[1];
  const float* Wq = (const float*)d_in[2];
  const float* bq = (const float*)d_in[3];
  const float* Wk = (const float*)d_in[4];
  const float* bk = (const float*)d_in[5];
  const float* Wv = (const float*)d_in[6];
  const float* bv = (const float*)d_in[7];
  const float* Wo = (const float*)d_in[8];
  const float* bo = (const float*)d_in[9];
  float* out = (float*)d_out;

  const int Mtok = 2 * 2048;  // 4096 tokens
  const int D = 1024;

  const size_t need = (size_t)Mtok * D * 2 * 5 + (size_t)D * D * 2 * 4;  // 48 MiB
  if (ws_size < need) return;

  char* p = (char*)d_ws;
  u16* xb  = (u16*)p; p += (size_t)Mtok * D * 2;
  u16* wqb = (u16*)p; p += (size_t)D * D * 2;
  u16* wkb = (u16*)p; p += (size_t)D * D * 2;
  u16* wvb = (u16*)p; p += (size_t)D * D * 2;
  u16* wob = (u16*)p; p += (size_t)D * D * 2;
  u16* Qb  = (u16*)p; p += (size_t)Mtok * D * 2;
  u16* Kb  = (u16*)p; p += (size_t)Mtok * D * 2;
  u16* Vtb = (u16*)p; p += (size_t)Mtok * D * 2;  // [b][h*64+hd][s]
  u16* Ob  = (u16*)p; p += (size_t)Mtok * D * 2;

  CastArgs ca;
  ca.src[0] = x;  ca.dst[0] = xb;  ca.n4[0] = Mtok * D / 4;
  ca.src[1] = Wq; ca.dst[1] = wqb; ca.n4[1] = D * D / 4;
  ca.src[2] = Wk; ca.dst[2] = wkb; ca.n4[2] = D * D / 4;
  ca.src[3] = Wv; ca.dst[3] = wvb; ca.n4[3] = D * D / 4;
  ca.src[4] = Wo; ca.dst[4] = wob; ca.n4[4] = D * D / 4;
  cast_f32_bf16_kernel<<<dim3(256, 5), 256, 0, stream>>>(ca);

  // fused QKV (BN=128, grid 768 = 3/CU): z=0 -> Q (alpha folds 1/8*log2e),
  // z=1 -> K, z=2 -> V^T
  const float qalpha = 0.125f * 1.44269504088896340736f;
  gemm_nt_kernel<false, 128><<<dim3(D / 128, Mtok / 128, 3), 256, 0, stream>>>(
      xb, wqb, wkb, wvb, bq, bk, bv, Qb, Kb, Vtb, Mtok, D, D, qalpha, 1.0f, 1.0f);

  attn_fwd_kernel<<<dim3(2048 / 128, 32), 256, 0, stream>>>(Qb, Kb, Vtb, mask, Ob);

  // out projection (BN=64, grid 512 = 2/CU; was 256 = 1/CU at BN=128)
  gemm_nt_kernel<true, 64><<<dim3(D / 64, Mtok / 128, 1), 256, 0, stream>>>(
      Ob, wob, wob, wob, bo, bo, bo, out, out, out, Mtok, D, D, 1.0f, 1.0f, 1.0f);
}